// Round 2
// baseline (953.884 us; speedup 1.0000x reference)
//
#include <hip/hip_runtime.h>
#include <utility>

#define NM 16
#define NS 16384
#define DIMV 512

// Compile-time loop: fold expression guarantees full expansion at the AST
// level. Every v[][] index below is a compile-time constant, so SROA promotes
// the whole array into VGPRs (rule #20: runtime-indexed arrays go to scratch).
template <typename F, int... Is>
__device__ __forceinline__ void sf_impl(F&& f, std::integer_sequence<int, Is...>) {
    (f(std::integral_constant<int, Is>{}), ...);
}
template <int N, typename F>
__device__ __forceinline__ void static_for(F&& f) {
    sf_impl(static_cast<F&&>(f), std::make_integer_sequence<int, N>{});
}

// TWO 64-lane waves per sample (256 dims each): v[16][4] = 64 VGPRs/lane
// instead of 128 -> crosses the VGPR=128 occupancy step -> 4 waves/SIMD
// (16 waves/CU) instead of 2 -> doubles memory-latency hiding for this
// load-burst / long-compute / store-burst shape.
//
// Wave-local butterfly gives a per-wave partial; cross-wave combine goes
// through a tiny double-buffered LDS slab (parity-indexed, so one barrier per
// reduction batch). Block = 256 threads = 4 waves = 2 samples.
__global__ __launch_bounds__(256, 4) void ortho_gs_kernel(const float* __restrict__ x,
                                                          float* __restrict__ out) {
    const int tid  = threadIdx.x;
    const int lane = tid & 63;
    const int w    = (tid >> 6) & 1;   // which half of the sample's 512 dims
    const int sLoc = tid >> 7;         // sample-in-block (0 or 1)
    const int s    = blockIdx.x * 2 + sLoc;

    // [parity][sampleLocal][j][wave] -- the two waves' partials are adjacent,
    // so readback is one broadcast ds_read_b64 (float2) per j.
    __shared__ float redD[2][2][NM][2];
    __shared__ float redN[2][2][2];

    float v[NM][4];

    // Load: for vector m, the two waves together read the sample's contiguous
    // 2KB row; each wave reads a contiguous 1KB chunk (float4 per lane).
    static_for<NM>([&](auto M) {
        constexpr int m = M.value;
        const float4* p = (const float4*)(x + (size_t)m * (size_t)NS * DIMV
                                            + (size_t)s * DIMV);
        float4 a = p[w * 64 + lane];
        v[m][0] = a.x; v[m][1] = a.y; v[m][2] = a.z; v[m][3] = a.w;
    });

    // Classical Gram-Schmidt, fully expanded (compile-time register indexing).
    static_for<NM>([&](auto I) {
        constexpr int i = I.value;
        constexpr int par = i & 1;

        if constexpr (i > 0) {
            float c[i];
            // Per-wave partial dot products of v[i] against previous basis.
            static_for<i>([&](auto J) {
                constexpr int j = J.value;
                float p = 0.f;
                static_for<4>([&](auto E) {
                    constexpr int e = E.value;
                    p = fmaf(v[i][e], v[j][e], p);
                });
                c[j] = p;
            });
            // Batched butterfly within the wave (independent per j).
            static_for<6>([&](auto ST) {
                constexpr int st = 1 << ST.value;
                static_for<i>([&](auto J) {
                    constexpr int j = J.value;
                    c[j] += __shfl_xor(c[j], st, 64);
                });
            });
            // Cross-wave combine via LDS (parity slot: one barrier suffices;
            // the same slot is rewritten 2 steps later, >=3 barriers away).
            if (lane == 0) {
                static_for<i>([&](auto J) {
                    constexpr int j = J.value;
                    redD[par][sLoc][j][w] = c[j];
                });
            }
            __syncthreads();
            static_for<i>([&](auto J) {
                constexpr int j = J.value;
                float2 t = *(const float2*)&redD[par][sLoc][j][0];
                c[j] = t.x + t.y;
            });
            // Subtract all projections (classical GS, like the reference).
            static_for<i>([&](auto J) {
                constexpr int j = J.value;
                static_for<4>([&](auto E) {
                    constexpr int e = E.value;
                    v[i][e] = fmaf(-c[j], v[j][e], v[i][e]);
                });
            });
        }

        // Normalize.
        float n = 0.f;
        static_for<4>([&](auto E) {
            constexpr int e = E.value;
            n = fmaf(v[i][e], v[i][e], n);
        });
        static_for<6>([&](auto ST) {
            constexpr int st = 1 << ST.value;
            n += __shfl_xor(n, st, 64);
        });
        if (lane == 0) redN[par][sLoc][w] = n;
        __syncthreads();
        {
            float2 t = *(const float2*)&redN[par][sLoc][0];
            n = t.x + t.y;
        }
        const float inv = 1.0f / sqrtf(n);
        static_for<4>([&](auto E) {
            constexpr int e = E.value;
            v[i][e] *= inv;
        });
    });

    // Store in the same layout: out[k, s, d].
    static_for<NM>([&](auto M) {
        constexpr int m = M.value;
        float4* p = (float4*)(out + (size_t)m * (size_t)NS * DIMV
                                  + (size_t)s * DIMV);
        p[w * 64 + lane] = make_float4(v[m][0], v[m][1], v[m][2], v[m][3]);
    });
}

extern "C" void kernel_launch(void* const* d_in, const int* in_sizes, int n_in,
                              void* d_out, int out_size, void* d_ws, size_t ws_size,
                              hipStream_t stream) {
    const float* x = (const float*)d_in[0];
    float* out = (float*)d_out;
    // Two waves per sample: 2 samples per 256-thread block.
    const int threads = 256;
    const int blocks = NS / 2;
    ortho_gs_kernel<<<blocks, threads, 0, stream>>>(x, out);
}

// Round 3
// 922.644 us; speedup vs baseline: 1.0339x; 1.0339x over previous
//
#include <hip/hip_runtime.h>
#include <utility>

#define NM 16
#define NS 16384
#define DIMV 512

// Compile-time loop: fold expression guarantees full expansion at the AST
// level; every array index below is a compile-time constant, so SROA keeps
// everything in VGPRs (rule #20: runtime-indexed arrays go to scratch).
template <typename F, int... Is>
__device__ __forceinline__ void sf_impl(F&& f, std::integer_sequence<int, Is...>) {
    (f(std::integral_constant<int, Is>{}), ...);
}
template <int N, typename F>
__device__ __forceinline__ void static_for(F&& f) {
    sf_impl(static_cast<F&&>(f), std::make_integer_sequence<int, N>{});
}

// One 64-lane wave per sample; v[16][8] register-resident (2x float4/vector).
//
// Gram-Cholesky Gram-Schmidt: classical GS == forward substitution B = L^-1 V
// where G = V V^T = L L^T  (L[i][j] = <v_i,b_j>, L[i][i] = ||w_i||).
//   1. G via 136 INDEPENDENT dots -> butterflies pipeline (no serial spine).
//   2. Cholesky on lane-distributed 16x16 (lane r holds row r, 16 VGPRs),
//      cross-lane only via compile-time-lane __shfl broadcasts.
//   3. Forward substitution: pure lane-local FMA, output normalized for free.
// Replaces ~200 DEPENDENT cross-lane ops of the stepwise GS with ~100
// pipelined ones. No LDS, no barriers.
__global__ __launch_bounds__(256, 2) void ortho_chol_kernel(const float* __restrict__ x,
                                                            float* __restrict__ out) {
    const int gtid = blockIdx.x * blockDim.x + threadIdx.x;
    const int s    = gtid >> 6;          // sample = global wave id
    const int lane = threadIdx.x & 63;
    if (s >= NS) return;

    float v[NM][8];

    // Load: for vector m, lanes read a contiguous 2KB row (two float4 each).
    static_for<NM>([&](auto M) {
        constexpr int m = M.value;
        const float4* p = (const float4*)(x + (size_t)m * (size_t)NS * DIMV
                                            + (size_t)s * DIMV);
        float4 a = p[lane];
        float4 b = p[64 + lane];
        v[m][0] = a.x; v[m][1] = a.y; v[m][2] = a.z; v[m][3] = a.w;
        v[m][4] = b.x; v[m][5] = b.y; v[m][6] = b.z; v[m][7] = b.w;
    });

    // Lower-triangular Gram matrix, lane-distributed: lane r (r<16) holds
    // row r entries j<=r in g[j]; other lanes/slots are never read.
    float g[NM];
    static_for<NM>([&](auto J) { g[J.value] = 0.f; });

    // --- 1. Gram: G[i][j] = <v_i, v_j>, row by row; rows are independent so
    // the 6-round butterflies pipeline across rows.
    static_for<NM>([&](auto I) {
        constexpr int i = I.value;
        float c[i + 1];
        static_for<i + 1>([&](auto J) {
            constexpr int j = J.value;
            float p = 0.f;
            static_for<8>([&](auto E) {
                constexpr int e = E.value;
                p = fmaf(v[i][e], v[j][e], p);
            });
            c[j] = p;
        });
        static_for<6>([&](auto ST) {
            constexpr int st = 1 << ST.value;
            static_for<i + 1>([&](auto J) {
                constexpr int j = J.value;
                c[j] += __shfl_xor(c[j], st, 64);
            });
        });
        if (lane == i) {
            static_for<i + 1>([&](auto J) {
                constexpr int j = J.value;
                g[j] = c[j];
            });
        }
    });

    // --- 2. In-place distributed Cholesky: lane r's g[] becomes row r of L.
    static_for<NM>([&](auto K) {
        constexpr int k = K.value;
        const float skk = __shfl(g[k], k, 64);   // updated G[k][k]
        const float inv = 1.0f / sqrtf(skk);     // wave-uniform
        if (lane >= k) g[k] *= inv;              // col k -> L[r][k]; lane k -> Lkk
        static_for<NM>([&](auto J) {
            constexpr int j = J.value;
            if constexpr (j > k) {
                const float Ljk = __shfl(g[k], j, 64);   // L[j][k] from lane j
                if (lane >= j) g[j] = fmaf(-g[k], Ljk, g[j]);
            }
        });
    });

    // --- 3. Forward substitution, in place: v[i] <- (v_i - sum L[i][j] b_j)/Lii.
    static_for<NM>([&](auto I) {
        constexpr int i = I.value;
        const float Lii = __shfl(g[i], i, 64);
        const float inv = 1.0f / Lii;
        float coef[i > 0 ? i : 1];
        static_for<i>([&](auto J) {
            constexpr int j = J.value;
            coef[j] = __shfl(g[j], i, 64);       // L[i][j] from lane i
        });
        static_for<8>([&](auto E) {
            constexpr int e = E.value;
            float a = v[i][e];
            static_for<i>([&](auto J) {
                constexpr int j = J.value;
                a = fmaf(-coef[j], v[j][e], a);
            });
            v[i][e] = a * inv;
        });
    });

    // Store in the same layout: out[k, s, d].
    static_for<NM>([&](auto M) {
        constexpr int m = M.value;
        float4* p = (float4*)(out + (size_t)m * (size_t)NS * DIMV
                                  + (size_t)s * DIMV);
        p[lane]      = make_float4(v[m][0], v[m][1], v[m][2], v[m][3]);
        p[64 + lane] = make_float4(v[m][4], v[m][5], v[m][6], v[m][7]);
    });
}

extern "C" void kernel_launch(void* const* d_in, const int* in_sizes, int n_in,
                              void* d_out, int out_size, void* d_ws, size_t ws_size,
                              hipStream_t stream) {
    const float* x = (const float*)d_in[0];
    float* out = (float*)d_out;
    // One wave per sample: 16384 waves; 4 waves per 256-thread block.
    const int threads = 256;
    const int waves_per_block = threads / 64;
    const int blocks = (NS + waves_per_block - 1) / waves_per_block;
    ortho_chol_kernel<<<blocks, threads, 0, stream>>>(x, out);
}